// Round 8
// baseline (1306.804 us; speedup 1.0000x reference)
//
#include <hip/hip_runtime.h>
#include <hip/hip_bf16.h>
#include <stdint.h>

// ---------------------------------------------------------------------------
// SwiGLU + int8 weight-quant emulation (VNNILinear), MI355X gfx950. Round 8:
//   Both GEMMs: 4-phase K-loop, depth-1 counted-lgkmcnt pipeline
//   {issue reads p+1 | wait lgkm(count) | 4 MFMA} x4, one barrier + one
//   vmcnt gate per tile, no full lgkm drains mid-tile. R7 swizzle kept
//   (q ^ ((r>>1)&3); residual 5e7 "conflicts" = free 2-way aliasing).
//   R7 post-mortem: LDS pipe 1408 cyc/tile vs MFMA 1178 ran ~serial with
//   2-phase structure; 4 phases balance ~290/~300 cyc per phase.
// ---------------------------------------------------------------------------

typedef short bf16x8 __attribute__((ext_vector_type(8)));
typedef float f32x4  __attribute__((ext_vector_type(4)));
typedef float f32x16 __attribute__((ext_vector_type(16)));
typedef int   i32x4  __attribute__((ext_vector_type(4)));
typedef int   i32x16 __attribute__((ext_vector_type(16)));

__device__ __forceinline__ unsigned short f2bf(float f) {
  unsigned u = __builtin_bit_cast(unsigned, f);
  u += 0x7FFFu + ((u >> 16) & 1u);   // RNE
  return (unsigned short)(u >> 16);
}

#define GLOAD_LDS16(gaddr, laddr)                                             \
  __builtin_amdgcn_global_load_lds(                                           \
      (const __attribute__((address_space(1))) void*)(gaddr),                 \
      (__attribute__((address_space(3))) void*)(laddr), 16, 0, 0)

#define FENCE()      asm volatile("" ::: "memory")
#define BAR()        __builtin_amdgcn_s_barrier()
#define WAIT_LGKM(n) asm volatile("s_waitcnt lgkmcnt(" #n ")" ::: "memory")
#define WAIT_VM8()   asm volatile("s_waitcnt vmcnt(8)" ::: "memory")
#define WAIT_VM4()   asm volatile("s_waitcnt vmcnt(4)" ::: "memory")
#define WAIT_VM0()   asm volatile("s_waitcnt vmcnt(0)" ::: "memory")
#define SFENCE()     __builtin_amdgcn_sched_barrier(0)
#define PRIO1()      __builtin_amdgcn_s_setprio(1)
#define PRIO0()      __builtin_amdgcn_s_setprio(0)

// --------------------------- preprocessing --------------------------------

__global__ void quant_rows_i8_kernel(const float* __restrict__ w,
                                     char* __restrict__ q,
                                     float* __restrict__ scale, int cols,
                                     float clip) {
  const int row = blockIdx.x;
  const float* wr = w + (size_t)row * cols;
  char* qr = q + (size_t)row * cols;

  float m = 0.f;
  for (int c = threadIdx.x * 4; c < cols; c += blockDim.x * 4) {
    float4 v = *reinterpret_cast<const float4*>(wr + c);
    m = fmaxf(m, fmaxf(fmaxf(fabsf(v.x), fabsf(v.y)),
                       fmaxf(fabsf(v.z), fabsf(v.w))));
  }
#pragma unroll
  for (int off = 32; off; off >>= 1) m = fmaxf(m, __shfl_xor(m, off));
  __shared__ float smax[4];
  if ((threadIdx.x & 63) == 0) smax[threadIdx.x >> 6] = m;
  __syncthreads();
  m = fmaxf(fmaxf(smax[0], smax[1]), fmaxf(smax[2], smax[3]));

  const float s = fmaxf(m, clip) / 127.0f;
  if (threadIdx.x == 0) scale[row] = s;
  for (int c = threadIdx.x * 4; c < cols; c += blockDim.x * 4) {
    float4 v = *reinterpret_cast<const float4*>(wr + c);
    int b0 = (int)rintf(v.x / s), b1 = (int)rintf(v.y / s);
    int b2 = (int)rintf(v.z / s), b3 = (int)rintf(v.w / s);
    unsigned pk = (b0 & 0xff) | ((b1 & 0xff) << 8) | ((b2 & 0xff) << 16)
                  | ((b3 & 0xff) << 24);
    *reinterpret_cast<unsigned*>(qr + c) = pk;
  }
}

__global__ void quant_rows_bf16_kernel(const float* __restrict__ w,
                                       unsigned short* __restrict__ wq,
                                       int cols) {
  const int row = blockIdx.x;
  const float* wr = w + (size_t)row * cols;
  unsigned short* wqr = wq + (size_t)row * cols;

  float m = 0.f;
  for (int c = threadIdx.x * 4; c < cols; c += blockDim.x * 4) {
    float4 v = *reinterpret_cast<const float4*>(wr + c);
    m = fmaxf(m, fmaxf(fmaxf(fabsf(v.x), fabsf(v.y)),
                       fmaxf(fabsf(v.z), fabsf(v.w))));
  }
#pragma unroll
  for (int off = 32; off; off >>= 1) m = fmaxf(m, __shfl_xor(m, off));
  __shared__ float smax[4];
  if ((threadIdx.x & 63) == 0) smax[threadIdx.x >> 6] = m;
  __syncthreads();
  m = fmaxf(fmaxf(smax[0], smax[1]), fmaxf(smax[2], smax[3]));

  const float s = fmaxf(m, 1e-6f) / 127.0f;
  for (int c = threadIdx.x * 4; c < cols; c += blockDim.x * 4) {
    float4 v = *reinterpret_cast<const float4*>(wr + c);
    ushort4 o;
    o.x = f2bf(rintf(v.x / s) * s);
    o.y = f2bf(rintf(v.y / s) * s);
    o.z = f2bf(rintf(v.z / s) * s);
    o.w = f2bf(rintf(v.w / s) * s);
    *reinterpret_cast<ushort4*>(wqr + c) = o;
  }
}

// ------------------------------ GEMMs -------------------------------------

__device__ __forceinline__ void xcd_swizzle(int& bx, int& by, int gx, int gy) {
  int nwg = gx * gy;              // both grids are % 8 == 0
  int bid = by * gx + bx;
  int cpx = nwg >> 3;
  int s = (bid & 7) * cpx + (bid >> 3);
  by = s / gx;
  bx = s % gx;
}

// Fused int8 GEMM: H = silu((xq@w1q^T)*sx*sw1) * ((xq@w3q^T)*sx*sw3), bf16.
// Tile 256x128, BK=64, 8 waves (2M x 4N), wave tile 128 rows x 32 dual-cols.
// LDS slot (32 KiB): A 256x64B [0,16K), B1 128x64B [16K,24K), B3 [24K,32K).
// Stored chunk = q ^ ((r>>1)&3)  [R7: conflict floor].
__global__ __launch_bounds__(512, 2)
void gemm_i8_swiglu_kernel(const char* __restrict__ Aq,
                           const char* __restrict__ B1q,
                           const char* __restrict__ B3q,
                           const float* __restrict__ sx,
                           const float* __restrict__ sw1,
                           const float* __restrict__ sw3,
                           unsigned short* __restrict__ H,
                           int M, int N, int K) {
  __shared__ alignas(1024) char lds[131072];   // 4 slots x 32 KiB

  int bx = blockIdx.x, by = blockIdx.y;
  xcd_swizzle(bx, by, gridDim.x, gridDim.y);
  const int brow = by * 256, bcol = bx * 128;

  const int t = threadIdx.x, lane = t & 63, w = t >> 6;
  const int wr = w >> 2, wc = w & 3;
  const int l31 = lane & 31, hi = lane >> 5;
  const int NT = K >> 6;   // BK=64

  const int rS = t >> 2;
  const int gcS = ((t & 3) ^ ((t >> 3) & 3)) * 16;
  const char* srcA  = Aq  + (size_t)(brow + rS) * K + gcS;
  const char* srcB1 = B1q + (size_t)(bcol + rS) * K + gcS;
  const char* srcB3 = B3q + (size_t)(bcol + rS) * K + gcS;

#define STAGE_A(kt)                                                           \
  {                                                                           \
    const int s2 = ((kt) & 3) * 32768;                                        \
    const size_t ko = (size_t)(kt) * 64;                                      \
    GLOAD_LDS16(srcA + ko, lds + s2 + t * 16);                                \
    GLOAD_LDS16(srcA + (size_t)128 * K + ko, lds + s2 + 8192 + t * 16);       \
  }
#define STAGE_B(kt)                                                           \
  {                                                                           \
    const int s2 = ((kt) & 3) * 32768;                                        \
    const size_t ko = (size_t)(kt) * 64;                                      \
    GLOAD_LDS16(srcB1 + ko, lds + s2 + 16384 + t * 16);                       \
    GLOAD_LDS16(srcB3 + ko, lds + s2 + 24576 + t * 16);                       \
  }

  STAGE_A(0); STAGE_B(0);
  STAGE_A(1); STAGE_B(1);
  STAGE_A(2); STAGE_B(2);
  WAIT_VM8();          // tile 0 landed (own share); barrier makes it global
  FENCE(); BAR();

  const int sx2 = (l31 >> 1) & 3;
  const int aoff  = (wr * 128 + l31) * 64 + ((hi ^ sx2) * 16);
  const int boff1 = 16384 + (wc * 32 + l31) * 64 + ((hi ^ sx2) * 16);
  const int boff3 = boff1 + 8192;

  i32x16 acc[4][2] = {};         // [m][B1|B3]

  for (int k = 0; k < NT; ++k) {
    const char* sl = lds + (k & 3) * 32768;
    const bool pf = (k + 3 < NT);
    i32x4 a00, a01, a02, a03, b01f, b03f;   // kh=0 frags
    i32x4 a10, a11, a12, a13, b11f, b13f;   // kh=1 frags

    // ---- Ph0: R0(4) + R1(2) issued; wait R0; MFMA m0,m1 @kh0 ----
    a00 = *reinterpret_cast<const i32x4*>(sl + aoff);
    a01 = *reinterpret_cast<const i32x4*>(sl + aoff + 2048);
    b01f = *reinterpret_cast<const i32x4*>(sl + boff1);
    b03f = *reinterpret_cast<const i32x4*>(sl + boff3);
    a02 = *reinterpret_cast<const i32x4*>(sl + aoff + 4096);
    a03 = *reinterpret_cast<const i32x4*>(sl + aoff + 6144);
    if (pf) STAGE_A(k + 3);
    WAIT_LGKM(2); SFENCE();
    PRIO1();
    acc[0][0] = __builtin_amdgcn_mfma_i32_32x32x32_i8(a00, b01f, acc[0][0], 0, 0, 0);
    acc[0][1] = __builtin_amdgcn_mfma_i32_32x32x32_i8(a00, b03f, acc[0][1], 0, 0, 0);
    acc[1][0] = __builtin_amdgcn_mfma_i32_32x32x32_i8(a01, b01f, acc[1][0], 0, 0, 0);
    acc[1][1] = __builtin_amdgcn_mfma_i32_32x32x32_i8(a01, b03f, acc[1][1], 0, 0, 0);
    PRIO0();

    // ---- Ph1: R2(4) issued; wait R1; MFMA m2,m3 @kh0 ----
    a10 = *reinterpret_cast<const i32x4*>(sl + (aoff ^ 32));
    a11 = *reinterpret_cast<const i32x4*>(sl + (aoff ^ 32) + 2048);
    b11f = *reinterpret_cast<const i32x4*>(sl + (boff1 ^ 32));
    b13f = *reinterpret_cast<const i32x4*>(sl + (boff3 ^ 32));
    WAIT_LGKM(4); SFENCE();
    PRIO1();
    acc[2][0] = __builtin_amdgcn_mfma_i32_32x32x32_i8(a02, b01f, acc[2][0], 0, 0, 0);
    acc[2][1] = __builtin_amdgcn_mfma_i32_32x32x32_i8(a02, b03f, acc[2][1], 0, 0, 0);
    acc[3][0] = __builtin_amdgcn_mfma_i32_32x32x32_i8(a03, b01f, acc[3][0], 0, 0, 0);
    acc[3][1] = __builtin_amdgcn_mfma_i32_32x32x32_i8(a03, b03f, acc[3][1], 0, 0, 0);
    PRIO0();

    // ---- Ph2: R3(2) issued; wait R2; MFMA m0,m1 @kh1 ----
    a12 = *reinterpret_cast<const i32x4*>(sl + (aoff ^ 32) + 4096);
    a13 = *reinterpret_cast<const i32x4*>(sl + (aoff ^ 32) + 6144);
    if (pf) STAGE_B(k + 3);
    WAIT_LGKM(2); SFENCE();
    PRIO1();
    acc[0][0] = __builtin_amdgcn_mfma_i32_32x32x32_i8(a10, b11f, acc[0][0], 0, 0, 0);
    acc[0][1] = __builtin_amdgcn_mfma_i32_32x32x32_i8(a10, b13f, acc[0][1], 0, 0, 0);
    acc[1][0] = __builtin_amdgcn_mfma_i32_32x32x32_i8(a11, b11f, acc[1][0], 0, 0, 0);
    acc[1][1] = __builtin_amdgcn_mfma_i32_32x32x32_i8(a11, b13f, acc[1][1], 0, 0, 0);
    PRIO0();

    // ---- Ph3: wait R3; MFMA m2,m3 @kh1; vm gate; barrier ----
    WAIT_LGKM(0); SFENCE();
    PRIO1();
    acc[2][0] = __builtin_amdgcn_mfma_i32_32x32x32_i8(a12, b11f, acc[2][0], 0, 0, 0);
    acc[2][1] = __builtin_amdgcn_mfma_i32_32x32x32_i8(a12, b13f, acc[2][1], 0, 0, 0);
    acc[3][0] = __builtin_amdgcn_mfma_i32_32x32x32_i8(a13, b11f, acc[3][0], 0, 0, 0);
    acc[3][1] = __builtin_amdgcn_mfma_i32_32x32x32_i8(a13, b13f, acc[3][1], 0, 0, 0);
    PRIO0();
    if (pf) {
      WAIT_VM8();                // slot k+1 landed (own share)
    } else if (k == NT - 3) {
      WAIT_VM4();
    } else if (k == NT - 2) {
      WAIT_VM0();
    }
    FENCE(); BAR();
  }
#undef STAGE_A
#undef STAGE_B

  // ---- epilogue: dequant + SwiGLU -> bf16 (verified R4-R7) ----
  const int ocol = bcol + wc * 32 + l31;
  const int rowb = brow + wr * 128 + 4 * hi;
  const float sw1c = sw1[ocol], sw3c = sw3[ocol];
#pragma unroll
  for (int m = 0; m < 4; ++m) {
#pragma unroll
    for (int rq = 0; rq < 4; ++rq) {
      const int r0 = rowb + m * 32 + 8 * rq;
      const f32x4 sx4 = *reinterpret_cast<const f32x4*>(sx + r0);
#pragma unroll
      for (int j = 0; j < 4; ++j) {
        float y1 = (float)acc[m][0][rq * 4 + j] * (sx4[j] * sw1c);
        float y3 = (float)acc[m][1][rq * 4 + j] * (sx4[j] * sw3c);
        float hv = (y1 / (1.f + __expf(-y1))) * y3;
        H[(size_t)(r0 + j) * N + ocol] = f2bf(hv);
      }
    }
  }
}

// bf16 GEMM: C = A @ B^T (fp32 out). Tile 256x256, BK=32, 32x32x16 MFMA,
// same 4-phase pipelined skeleton. Stored chunk = q ^ ((r>>1)&3).
__global__ __launch_bounds__(512, 2)
void gemm_bf16_kernel(const unsigned short* __restrict__ A,
                      const unsigned short* __restrict__ B,
                      float* __restrict__ C, int M, int N, int K) {
  __shared__ alignas(1024) unsigned short lds[65536];  // 4 slots x 32 KiB

  int bx = blockIdx.x, by = blockIdx.y;
  xcd_swizzle(bx, by, gridDim.x, gridDim.y);
  const int brow = by * 256, bcol = bx * 256;

  const int t = threadIdx.x, lane = t & 63, w = t >> 6;
  const int wr = w >> 2, wc = w & 3;
  const int l31 = lane & 31, hi = lane >> 5;
  const int NT = K >> 5;   // BK=32

  const int rS = t >> 2;
  const int cS = ((t & 3) ^ ((t >> 3) & 3)) * 8;   // sh units
  const unsigned short* srcA = A + (size_t)(brow + rS) * K + cS;
  const unsigned short* srcB = B + (size_t)(bcol + rS) * K + cS;

#define STAGE_A(kt)                                                           \
  {                                                                           \
    const int s2 = ((kt) & 3) * 16384;                                        \
    const size_t ko = (size_t)(kt) * 32;                                      \
    GLOAD_LDS16(srcA + ko, &lds[s2 + t * 8]);                                 \
    GLOAD_LDS16(srcA + (size_t)128 * K + ko, &lds[s2 + 4096 + t * 8]);        \
  }
#define STAGE_B(kt)                                                           \
  {                                                                           \
    const int s2 = ((kt) & 3) * 16384;                                        \
    const size_t ko = (size_t)(kt) * 32;                                      \
    GLOAD_LDS16(srcB + ko, &lds[s2 + 8192 + t * 8]);                          \
    GLOAD_LDS16(srcB + (size_t)128 * K + ko, &lds[s2 + 12288 + t * 8]);       \
  }

  STAGE_A(0); STAGE_B(0);
  STAGE_A(1); STAGE_B(1);
  STAGE_A(2); STAGE_B(2);
  WAIT_VM8();
  FENCE(); BAR();

  const int sx2 = (l31 >> 1) & 3;
  const int aoff  = (wr * 128 + l31) * 32 + ((hi ^ sx2) * 8);
  const int boff0 = 8192 + (wc * 64 + l31) * 32 + ((hi ^ sx2) * 8);

  f32x16 acc[4][2] = {};

  for (int k = 0; k < NT; ++k) {
    const unsigned short* sl = &lds[(k & 3) * 16384];
    const bool pf = (k + 3 < NT);
    bf16x8 a00, a01, a02, a03, b00, b01;   // kh=0
    bf16x8 a10, a11, a12, a13, b10, b11;   // kh=1

    // ---- Ph0 ----
    a00 = *reinterpret_cast<const bf16x8*>(sl + aoff);
    a01 = *reinterpret_cast<const bf16x8*>(sl + aoff + 1024);
    b00 = *reinterpret_cast<const bf16x8*>(sl + boff0);
    b01 = *reinterpret_cast<const bf16x8*>(sl + boff0 + 1024);
    a02 = *reinterpret_cast<const bf16x8*>(sl + aoff + 2048);
    a03 = *reinterpret_cast<const bf16x8*>(sl + aoff + 3072);
    if (pf) STAGE_A(k + 3);
    WAIT_LGKM(2); SFENCE();
    PRIO1();
    acc[0][0] = __builtin_amdgcn_mfma_f32_32x32x16_bf16(a00, b00, acc[0][0], 0, 0, 0);
    acc[0][1] = __builtin_amdgcn_mfma_f32_32x32x16_bf16(a00, b01, acc[0][1], 0, 0, 0);
    acc[1][0] = __builtin_amdgcn_mfma_f32_32x32x16_bf16(a01, b00, acc[1][0], 0, 0, 0);
    acc[1][1] = __builtin_amdgcn_mfma_f32_32x32x16_bf16(a01, b01, acc[1][1], 0, 0, 0);
    PRIO0();

    // ---- Ph1 ----
    a10 = *reinterpret_cast<const bf16x8*>(sl + (aoff ^ 16));
    a11 = *reinterpret_cast<const bf16x8*>(sl + (aoff ^ 16) + 1024);
    b10 = *reinterpret_cast<const bf16x8*>(sl + (boff0 ^ 16));
    b11 = *reinterpret_cast<const bf16x8*>(sl + ((boff0 + 1024) ^ 16));
    WAIT_LGKM(4); SFENCE();
    PRIO1();
    acc[2][0] = __builtin_amdgcn_mfma_f32_32x32x16_bf16(a02, b00, acc[2][0], 0, 0, 0);
    acc[2][1] = __builtin_amdgcn_mfma_f32_32x32x16_bf16(a02, b01, acc[2][1], 0, 0, 0);
    acc[3][0] = __builtin_amdgcn_mfma_f32_32x32x16_bf16(a03, b00, acc[3][0], 0, 0, 0);
    acc[3][1] = __builtin_amdgcn_mfma_f32_32x32x16_bf16(a03, b01, acc[3][1], 0, 0, 0);
    PRIO0();

    // ---- Ph2 ----
    a12 = *reinterpret_cast<const bf16x8*>(sl + (aoff ^ 16) + 2048);
    a13 = *reinterpret_cast<const bf16x8*>(sl + (aoff ^ 16) + 3072);
    if (pf) STAGE_B(k + 3);
    WAIT_LGKM(2); SFENCE();
    PRIO1();
    acc[0][0] = __builtin_amdgcn_mfma_f32_32x32x16_bf16(a10, b10, acc[0][0], 0, 0, 0);
    acc[0][1] = __builtin_amdgcn_mfma_f32_32x32x16_bf16(a10, b11, acc[0][1], 0, 0, 0);
    acc[1][0] = __builtin_amdgcn_mfma_f32_32x32x16_bf16(a11, b10, acc[1][0], 0, 0, 0);
    acc[1][1] = __builtin_amdgcn_mfma_f32_32x32x16_bf16(a11, b11, acc[1][1], 0, 0, 0);
    PRIO0();

    // ---- Ph3 ----
    WAIT_LGKM(0); SFENCE();
    PRIO1();
    acc[2][0] = __builtin_amdgcn_mfma_f32_32x32x16_bf16(a12, b10, acc[2][0], 0, 0, 0);
    acc[2][1] = __builtin_amdgcn_mfma_f32_32x32x16_bf16(a12, b11, acc[2][1], 0, 0, 0);
    acc[3][0] = __builtin_amdgcn_mfma_f32_32x32x16_bf16(a13, b10, acc[3][0], 0, 0, 0);
    acc[3][1] = __builtin_amdgcn_mfma_f32_32x32x16_bf16(a13, b11, acc[3][1], 0, 0, 0);
    PRIO0();
    if (pf) {
      WAIT_VM8();
    } else if (k == NT - 3) {
      WAIT_VM4();
    } else if (k == NT - 2) {
      WAIT_VM0();
    }
    FENCE(); BAR();
  }
#undef STAGE_A
#undef STAGE_B

  const int ocol = bcol + wc * 64 + l31;
  const int rowb = brow + wr * 128 + 4 * hi;
#pragma unroll
  for (int m = 0; m < 4; ++m)
#pragma unroll
    for (int n = 0; n < 2; ++n)
#pragma unroll
      for (int rq = 0; rq < 4; ++rq)
#pragma unroll
        for (int j = 0; j < 4; ++j)
          C[(size_t)(rowb + m * 32 + 8 * rq + j) * N + (ocol + n * 32)] =
              acc[m][n][rq * 4 + j];
}

// ------------------------------ launch -------------------------------------

extern "C" void kernel_launch(void* const* d_in, const int* in_sizes, int n_in,
                              void* d_out, int out_size, void* d_ws,
                              size_t ws_size, hipStream_t stream) {
  const float* x  = (const float*)d_in[0];
  const float* w1 = (const float*)d_in[1];
  const float* w2 = (const float*)d_in[2];
  const float* w3 = (const float*)d_in[3];
  float* out = (float*)d_out;

  const int DIM = 4096, HID = 8192;
  const int M = in_sizes[0] / DIM;  // 8192

  char* xq  = (char*)d_ws;                              // M*DIM    (32 MB)
  char* w1q = xq + (size_t)M * DIM;                     // HID*DIM  (32 MB)
  char* w3q = w1q + (size_t)HID * DIM;                  // HID*DIM  (32 MB)
  unsigned short* w2b = (unsigned short*)(w3q + (size_t)HID * DIM);  // 64 MB
  unsigned short* h = w2b + (size_t)DIM * HID;          // M*HID bf16 (128 MB)
  float* sx  = (float*)(h + (size_t)M * HID);           // M
  float* sw1 = sx + M;                                  // HID
  float* sw3 = sw1 + HID;                               // HID

  quant_rows_i8_kernel<<<HID, 256, 0, stream>>>(w1, w1q, sw1, DIM, 1e-6f);
  quant_rows_i8_kernel<<<HID, 256, 0, stream>>>(w3, w3q, sw3, DIM, 1e-6f);
  quant_rows_i8_kernel<<<M, 256, 0, stream>>>(x, xq, sx, DIM, 1e-30f);
  quant_rows_bf16_kernel<<<DIM, 256, 0, stream>>>(w2, w2b, HID);

  gemm_i8_swiglu_kernel<<<dim3(HID / 128, M / 256), 512, 0, stream>>>(
      xq, w1q, w3q, sx, sw1, sw3, h, M, HID, DIM);
  gemm_bf16_kernel<<<dim3(DIM / 256, M / 256), 512, 0, stream>>>(
      h, w2b, out, M, DIM, HID);
}

// Round 9
// 1235.278 us; speedup vs baseline: 1.0579x; 1.0579x over previous
//
#include <hip/hip_runtime.h>
#include <hip/hip_bf16.h>
#include <stdint.h>

// ---------------------------------------------------------------------------
// SwiGLU + int8 weight-quant emulation (VNNILinear), MI355X gfx950. Round 9:
//   R7 schedule restored (R8's 4-phase split regressed: bursts too short).
//   NEW: K-loop unrolled by slot period 4 -> compile-time LDS slot offsets
//   (ds_read base+imm, zero VALU) + per-group DMA pointers (offset folds into
//   global_load_lds imm). Last 4 tiles peeled into generic tail.
//   R7 PM: MfmaUtil 47 + VALU 25 -> ~670 cyc/tile of addressing VALU is the
//   third pipe; this round removes most of it.
// ---------------------------------------------------------------------------

typedef short bf16x8 __attribute__((ext_vector_type(8)));
typedef float f32x4  __attribute__((ext_vector_type(4)));
typedef float f32x16 __attribute__((ext_vector_type(16)));
typedef int   i32x4  __attribute__((ext_vector_type(4)));
typedef int   i32x16 __attribute__((ext_vector_type(16)));

__device__ __forceinline__ unsigned short f2bf(float f) {
  unsigned u = __builtin_bit_cast(unsigned, f);
  u += 0x7FFFu + ((u >> 16) & 1u);   // RNE
  return (unsigned short)(u >> 16);
}

#define GLOAD_LDS16(gaddr, laddr)                                             \
  __builtin_amdgcn_global_load_lds(                                           \
      (const __attribute__((address_space(1))) void*)(gaddr),                 \
      (__attribute__((address_space(3))) void*)(laddr), 16, 0, 0)

#define FENCE()      asm volatile("" ::: "memory")
#define BAR()        __builtin_amdgcn_s_barrier()
#define WAIT_LGKM(n) asm volatile("s_waitcnt lgkmcnt(" #n ")" ::: "memory")
#define WAIT_VM8()   asm volatile("s_waitcnt vmcnt(8)" ::: "memory")
#define WAIT_VM4()   asm volatile("s_waitcnt vmcnt(4)" ::: "memory")
#define WAIT_VM0()   asm volatile("s_waitcnt vmcnt(0)" ::: "memory")
#define SFENCE()     __builtin_amdgcn_sched_barrier(0)
#define PRIO1()      __builtin_amdgcn_s_setprio(1)
#define PRIO0()      __builtin_amdgcn_s_setprio(0)

// --------------------------- preprocessing --------------------------------

__global__ void quant_rows_i8_kernel(const float* __restrict__ w,
                                     char* __restrict__ q,
                                     float* __restrict__ scale, int cols,
                                     float clip) {
  const int row = blockIdx.x;
  const float* wr = w + (size_t)row * cols;
  char* qr = q + (size_t)row * cols;

  float m = 0.f;
  for (int c = threadIdx.x * 4; c < cols; c += blockDim.x * 4) {
    float4 v = *reinterpret_cast<const float4*>(wr + c);
    m = fmaxf(m, fmaxf(fmaxf(fabsf(v.x), fabsf(v.y)),
                       fmaxf(fabsf(v.z), fabsf(v.w))));
  }
#pragma unroll
  for (int off = 32; off; off >>= 1) m = fmaxf(m, __shfl_xor(m, off));
  __shared__ float smax[4];
  if ((threadIdx.x & 63) == 0) smax[threadIdx.x >> 6] = m;
  __syncthreads();
  m = fmaxf(fmaxf(smax[0], smax[1]), fmaxf(smax[2], smax[3]));

  const float s = fmaxf(m, clip) / 127.0f;
  if (threadIdx.x == 0) scale[row] = s;
  for (int c = threadIdx.x * 4; c < cols; c += blockDim.x * 4) {
    float4 v = *reinterpret_cast<const float4*>(wr + c);
    int b0 = (int)rintf(v.x / s), b1 = (int)rintf(v.y / s);
    int b2 = (int)rintf(v.z / s), b3 = (int)rintf(v.w / s);
    unsigned pk = (b0 & 0xff) | ((b1 & 0xff) << 8) | ((b2 & 0xff) << 16)
                  | ((b3 & 0xff) << 24);
    *reinterpret_cast<unsigned*>(qr + c) = pk;
  }
}

__global__ void quant_rows_bf16_kernel(const float* __restrict__ w,
                                       unsigned short* __restrict__ wq,
                                       int cols) {
  const int row = blockIdx.x;
  const float* wr = w + (size_t)row * cols;
  unsigned short* wqr = wq + (size_t)row * cols;

  float m = 0.f;
  for (int c = threadIdx.x * 4; c < cols; c += blockDim.x * 4) {
    float4 v = *reinterpret_cast<const float4*>(wr + c);
    m = fmaxf(m, fmaxf(fmaxf(fabsf(v.x), fabsf(v.y)),
                       fmaxf(fabsf(v.z), fabsf(v.w))));
  }
#pragma unroll
  for (int off = 32; off; off >>= 1) m = fmaxf(m, __shfl_xor(m, off));
  __shared__ float smax[4];
  if ((threadIdx.x & 63) == 0) smax[threadIdx.x >> 6] = m;
  __syncthreads();
  m = fmaxf(fmaxf(smax[0], smax[1]), fmaxf(smax[2], smax[3]));

  const float s = fmaxf(m, 1e-6f) / 127.0f;
  for (int c = threadIdx.x * 4; c < cols; c += blockDim.x * 4) {
    float4 v = *reinterpret_cast<const float4*>(wr + c);
    ushort4 o;
    o.x = f2bf(rintf(v.x / s) * s);
    o.y = f2bf(rintf(v.y / s) * s);
    o.z = f2bf(rintf(v.z / s) * s);
    o.w = f2bf(rintf(v.w / s) * s);
    *reinterpret_cast<ushort4*>(wqr + c) = o;
  }
}

// ------------------------------ GEMMs -------------------------------------

__device__ __forceinline__ void xcd_swizzle(int& bx, int& by, int gx, int gy) {
  int nwg = gx * gy;              // both grids are % 8 == 0
  int bid = by * gx + bx;
  int cpx = nwg >> 3;
  int s = (bid & 7) * cpx + (bid >> 3);
  by = s / gx;
  bx = s % gx;
}

// Fused int8 GEMM: H = silu((xq@w1q^T)*sx*sw1) * ((xq@w3q^T)*sx*sw3), bf16.
// Tile 256x128, BK=64, 8 waves (2M x 4N), wave tile 128 rows x 32 dual-cols.
// LDS slot (32 KiB): A 256x64B [0,16K), B1 128x64B [16K,24K), B3 [24K,32K).
// Stored chunk = q ^ ((r>>1)&3). R7 schedule; slot-unrolled main loop.
__global__ __launch_bounds__(512, 2)
void gemm_i8_swiglu_kernel(const char* __restrict__ Aq,
                           const char* __restrict__ B1q,
                           const char* __restrict__ B3q,
                           const float* __restrict__ sx,
                           const float* __restrict__ sw1,
                           const float* __restrict__ sw3,
                           unsigned short* __restrict__ H,
                           int M, int N, int K) {
  __shared__ alignas(1024) char lds[131072];   // 4 slots x 32 KiB

  int bx = blockIdx.x, by = blockIdx.y;
  xcd_swizzle(bx, by, gridDim.x, gridDim.y);
  const int brow = by * 256, bcol = bx * 128;

  const int t = threadIdx.x, lane = t & 63, w = t >> 6;
  const int wr = w >> 2, wc = w & 3;
  const int l31 = lane & 31, hi = lane >> 5;
  const int NT = K >> 6;   // BK=64

  const int rS = t >> 2;
  const int gcS = ((t & 3) ^ ((t >> 3) & 3)) * 16;
  const char* srcA  = Aq  + (size_t)(brow + rS) * K + gcS;
  const char* srcB1 = B1q + (size_t)(bcol + rS) * K + gcS;
  const char* srcB3 = B3q + (size_t)(bcol + rS) * K + gcS;

#define STAGE_A(kt)                                                           \
  {                                                                           \
    const int s2 = ((kt) & 3) * 32768;                                        \
    const size_t ko = (size_t)(kt) * 64;                                      \
    GLOAD_LDS16(srcA + ko, lds + s2 + t * 16);                                \
    GLOAD_LDS16(srcA + (size_t)128 * K + ko, lds + s2 + 8192 + t * 16);       \
  }
#define STAGE_B(kt)                                                           \
  {                                                                           \
    const int s2 = ((kt) & 3) * 32768;                                        \
    const size_t ko = (size_t)(kt) * 64;                                      \
    GLOAD_LDS16(srcB1 + ko, lds + s2 + 16384 + t * 16);                       \
    GLOAD_LDS16(srcB3 + ko, lds + s2 + 24576 + t * 16);                       \
  }

  STAGE_A(0); STAGE_B(0);
  STAGE_A(1); STAGE_B(1);
  STAGE_A(2); STAGE_B(2);
  WAIT_VM8();          // tile 0 landed (own share); barrier makes it global
  FENCE(); BAR();

  const int sx2 = (l31 >> 1) & 3;
  const int aoff  = (wr * 128 + l31) * 64 + ((hi ^ sx2) * 16);
  const int boff1 = 16384 + (wc * 32 + l31) * 64 + ((hi ^ sx2) * 16);
  const int boff3 = boff1 + 8192;

  i32x16 acc[4][2] = {};         // [m][B1|B3]
  i32x4 a0[4], b10, b30;         // set0: kh=0 frags
  i32x4 a1[4], b11, b31;         // set1: kh=1 frags

  // preload set0 = (tile 0, kh0)
#pragma unroll
  for (int m = 0; m < 4; ++m)
    a0[m] = *reinterpret_cast<const i32x4*>(lds + aoff + m * 2048);
  b10 = *reinterpret_cast<const i32x4*>(lds + boff1);
  b30 = *reinterpret_cast<const i32x4*>(lds + boff3);

#define MFMA8(ar, b1r, b3r)                                                   \
  acc[0][0] = __builtin_amdgcn_mfma_i32_32x32x32_i8(ar[0], b1r, acc[0][0], 0, 0, 0); \
  acc[0][1] = __builtin_amdgcn_mfma_i32_32x32x32_i8(ar[0], b3r, acc[0][1], 0, 0, 0); \
  acc[1][0] = __builtin_amdgcn_mfma_i32_32x32x32_i8(ar[1], b1r, acc[1][0], 0, 0, 0); \
  acc[1][1] = __builtin_amdgcn_mfma_i32_32x32x32_i8(ar[1], b3r, acc[1][1], 0, 0, 0); \
  acc[2][0] = __builtin_amdgcn_mfma_i32_32x32x32_i8(ar[2], b1r, acc[2][0], 0, 0, 0); \
  acc[2][1] = __builtin_amdgcn_mfma_i32_32x32x32_i8(ar[2], b3r, acc[2][1], 0, 0, 0); \
  acc[3][0] = __builtin_amdgcn_mfma_i32_32x32x32_i8(ar[3], b1r, acc[3][0], 0, 0, 0); \
  acc[3][1] = __builtin_amdgcn_mfma_i32_32x32x32_i8(ar[3], b3r, acc[3][1], 0, 0, 0)

  // ---- main loop: groups of 4 tiles, slot index = unroll constant ----
  int kb = 0;
  for (; kb < NT - 4; kb += 4) {
    const char* pA  = srcA  + (size_t)kb * 64;
    const char* pB1 = srcB1 + (size_t)kb * 64;
    const char* pB3 = srcB3 + (size_t)kb * 64;
#pragma unroll
    for (int s = 0; s < 4; ++s) {
      const char* sl = lds + s * 32768;                 // slot of tile kb+s
      const char* sn = lds + (((s + 1) & 3) * 32768);   // slot of tile kb+s+1
      char* sp = lds + (((s + 3) & 3) * 32768);         // stage dest slot
      const int ko = (s + 3) * 64;                      // folds into DMA imm

      // ---- P1: issue set1 reads; STAGE_A; wait set0; MFMA set0 ----
      a1[0] = *reinterpret_cast<const i32x4*>(sl + (aoff ^ 32));
      a1[1] = *reinterpret_cast<const i32x4*>(sl + (aoff ^ 32) + 2048);
      a1[2] = *reinterpret_cast<const i32x4*>(sl + (aoff ^ 32) + 4096);
      a1[3] = *reinterpret_cast<const i32x4*>(sl + (aoff ^ 32) + 6144);
      b11 = *reinterpret_cast<const i32x4*>(sl + (boff1 ^ 32));
      b31 = *reinterpret_cast<const i32x4*>(sl + (boff3 ^ 32));
      GLOAD_LDS16(pA + ko, sp + t * 16);
      GLOAD_LDS16(pA + (size_t)128 * K + ko, sp + 8192 + t * 16);
      WAIT_LGKM(6); SFENCE();
      PRIO1(); MFMA8(a0, b10, b30); PRIO0();

      // ---- P2: STAGE_B; vm gate; drain reads; BAR; next set0; MFMA set1 ----
      GLOAD_LDS16(pB1 + ko, sp + 16384 + t * 16);
      GLOAD_LDS16(pB3 + ko, sp + 24576 + t * 16);
      WAIT_VM8();
      WAIT_LGKM(0);
      FENCE(); BAR();
      a0[0] = *reinterpret_cast<const i32x4*>(sn + aoff);
      a0[1] = *reinterpret_cast<const i32x4*>(sn + aoff + 2048);
      a0[2] = *reinterpret_cast<const i32x4*>(sn + aoff + 4096);
      a0[3] = *reinterpret_cast<const i32x4*>(sn + aoff + 6144);
      b10 = *reinterpret_cast<const i32x4*>(sn + boff1);
      b30 = *reinterpret_cast<const i32x4*>(sn + boff3);
      SFENCE();
      PRIO1(); MFMA8(a1, b11, b31); PRIO0();
    }
  }

  // ---- tail: last 4 tiles, R7 generic body ----
  for (int k = kb; k < NT; ++k) {
    const char* sl = lds + (k & 3) * 32768;
    const bool pf = (k + 3 < NT);

    a1[0] = *reinterpret_cast<const i32x4*>(sl + (aoff ^ 32));
    a1[1] = *reinterpret_cast<const i32x4*>(sl + (aoff ^ 32) + 2048);
    a1[2] = *reinterpret_cast<const i32x4*>(sl + (aoff ^ 32) + 4096);
    a1[3] = *reinterpret_cast<const i32x4*>(sl + (aoff ^ 32) + 6144);
    b11 = *reinterpret_cast<const i32x4*>(sl + (boff1 ^ 32));
    b31 = *reinterpret_cast<const i32x4*>(sl + (boff3 ^ 32));
    if (pf) STAGE_A(k + 3);
    WAIT_LGKM(6); SFENCE();
    PRIO1(); MFMA8(a0, b10, b30); PRIO0();

    if (pf) {
      STAGE_B(k + 3);
      WAIT_VM8();
    } else if (k == NT - 3) {
      WAIT_VM4();
    } else if (k == NT - 2) {
      WAIT_VM0();
    }
    WAIT_LGKM(0);
    FENCE(); BAR();
    if (k + 1 < NT) {
      const char* sn = lds + ((k + 1) & 3) * 32768;
      a0[0] = *reinterpret_cast<const i32x4*>(sn + aoff);
      a0[1] = *reinterpret_cast<const i32x4*>(sn + aoff + 2048);
      a0[2] = *reinterpret_cast<const i32x4*>(sn + aoff + 4096);
      a0[3] = *reinterpret_cast<const i32x4*>(sn + aoff + 6144);
      b10 = *reinterpret_cast<const i32x4*>(sn + boff1);
      b30 = *reinterpret_cast<const i32x4*>(sn + boff3);
    }
    SFENCE();
    PRIO1(); MFMA8(a1, b11, b31); PRIO0();
  }
#undef MFMA8
#undef STAGE_A
#undef STAGE_B

  // ---- epilogue: dequant + SwiGLU -> bf16 (verified R4-R8) ----
  const int ocol = bcol + wc * 32 + l31;
  const int rowb = brow + wr * 128 + 4 * hi;
  const float sw1c = sw1[ocol], sw3c = sw3[ocol];
#pragma unroll
  for (int m = 0; m < 4; ++m) {
#pragma unroll
    for (int rq = 0; rq < 4; ++rq) {
      const int r0 = rowb + m * 32 + 8 * rq;
      const f32x4 sx4 = *reinterpret_cast<const f32x4*>(sx + r0);
#pragma unroll
      for (int j = 0; j < 4; ++j) {
        float y1 = (float)acc[m][0][rq * 4 + j] * (sx4[j] * sw1c);
        float y3 = (float)acc[m][1][rq * 4 + j] * (sx4[j] * sw3c);
        float hv = (y1 / (1.f + __expf(-y1))) * y3;
        H[(size_t)(r0 + j) * N + ocol] = f2bf(hv);
      }
    }
  }
}

// bf16 GEMM: C = A @ B^T (fp32 out). Tile 256x256, BK=32, 32x32x16 MFMA,
// R7 schedule, slot-unrolled main loop. Stored chunk = q ^ ((r>>1)&3).
__global__ __launch_bounds__(512, 2)
void gemm_bf16_kernel(const unsigned short* __restrict__ A,
                      const unsigned short* __restrict__ B,
                      float* __restrict__ C, int M, int N, int K) {
  __shared__ alignas(1024) unsigned short lds[65536];  // 4 slots x 32 KiB

  int bx = blockIdx.x, by = blockIdx.y;
  xcd_swizzle(bx, by, gridDim.x, gridDim.y);
  const int brow = by * 256, bcol = bx * 256;

  const int t = threadIdx.x, lane = t & 63, w = t >> 6;
  const int wr = w >> 2, wc = w & 3;
  const int l31 = lane & 31, hi = lane >> 5;
  const int NT = K >> 5;   // BK=32

  const int rS = t >> 2;
  const int cS = ((t & 3) ^ ((t >> 3) & 3)) * 8;   // sh units
  const unsigned short* srcA = A + (size_t)(brow + rS) * K + cS;
  const unsigned short* srcB = B + (size_t)(bcol + rS) * K + cS;

#define STAGE_A(kt)                                                           \
  {                                                                           \
    const int s2 = ((kt) & 3) * 16384;                                        \
    const size_t ko = (size_t)(kt) * 32;                                      \
    GLOAD_LDS16(srcA + ko, &lds[s2 + t * 8]);                                 \
    GLOAD_LDS16(srcA + (size_t)128 * K + ko, &lds[s2 + 4096 + t * 8]);        \
  }
#define STAGE_B(kt)                                                           \
  {                                                                           \
    const int s2 = ((kt) & 3) * 16384;                                        \
    const size_t ko = (size_t)(kt) * 32;                                      \
    GLOAD_LDS16(srcB + ko, &lds[s2 + 8192 + t * 8]);                          \
    GLOAD_LDS16(srcB + (size_t)128 * K + ko, &lds[s2 + 12288 + t * 8]);       \
  }

  STAGE_A(0); STAGE_B(0);
  STAGE_A(1); STAGE_B(1);
  STAGE_A(2); STAGE_B(2);
  WAIT_VM8();
  FENCE(); BAR();

  const int sx2 = (l31 >> 1) & 3;
  const int aoff  = (wr * 128 + l31) * 32 + ((hi ^ sx2) * 8);
  const int boff0 = 8192 + (wc * 64 + l31) * 32 + ((hi ^ sx2) * 8);

  f32x16 acc[4][2] = {};
  bf16x8 a0[4], b00, b01;    // set0: kh=0
  bf16x8 a1[4], b10, b11;    // set1: kh=1

#pragma unroll
  for (int m = 0; m < 4; ++m)
    a0[m] = *reinterpret_cast<const bf16x8*>(&lds[aoff + m * 1024]);
  b00 = *reinterpret_cast<const bf16x8*>(&lds[boff0]);
  b01 = *reinterpret_cast<const bf16x8*>(&lds[boff0 + 1024]);

#define MFMA8(ar, bx0, bx1)                                                   \
  acc[0][0] = __builtin_amdgcn_mfma_f32_32x32x16_bf16(ar[0], bx0, acc[0][0], 0, 0, 0); \
  acc[0][1] = __builtin_amdgcn_mfma_f32_32x32x16_bf16(ar[0], bx1, acc[0][1], 0, 0, 0); \
  acc[1][0] = __builtin_amdgcn_mfma_f32_32x32x16_bf16(ar[1], bx0, acc[1][0], 0, 0, 0); \
  acc[1][1] = __builtin_amdgcn_mfma_f32_32x32x16_bf16(ar[1], bx1, acc[1][1], 0, 0, 0); \
  acc[2][0] = __builtin_amdgcn_mfma_f32_32x32x16_bf16(ar[2], bx0, acc[2][0], 0, 0, 0); \
  acc[2][1] = __builtin_amdgcn_mfma_f32_32x32x16_bf16(ar[2], bx1, acc[2][1], 0, 0, 0); \
  acc[3][0] = __builtin_amdgcn_mfma_f32_32x32x16_bf16(ar[3], bx0, acc[3][0], 0, 0, 0); \
  acc[3][1] = __builtin_amdgcn_mfma_f32_32x32x16_bf16(ar[3], bx1, acc[3][1], 0, 0, 0)

  int kb = 0;
  for (; kb < NT - 4; kb += 4) {
    const unsigned short* pA = srcA + (size_t)kb * 32;
    const unsigned short* pB = srcB + (size_t)kb * 32;
#pragma unroll
    for (int s = 0; s < 4; ++s) {
      const unsigned short* sl = lds + s * 16384;
      const unsigned short* sn = lds + (((s + 1) & 3) * 16384);
      unsigned short* sp = lds + (((s + 3) & 3) * 16384);
      const int ko = (s + 3) * 32;

      // ---- P1 ----
      a1[0] = *reinterpret_cast<const bf16x8*>(sl + (aoff ^ 16));
      a1[1] = *reinterpret_cast<const bf16x8*>(sl + (aoff ^ 16) + 1024);
      a1[2] = *reinterpret_cast<const bf16x8*>(sl + (aoff ^ 16) + 2048);
      a1[3] = *reinterpret_cast<const bf16x8*>(sl + (aoff ^ 16) + 3072);
      b10 = *reinterpret_cast<const bf16x8*>(sl + (boff0 ^ 16));
      b11 = *reinterpret_cast<const bf16x8*>(sl + ((boff0 + 1024) ^ 16));
      GLOAD_LDS16(pA + ko, sp + t * 8);
      GLOAD_LDS16(pA + (size_t)128 * K + ko, sp + 4096 + t * 8);
      WAIT_LGKM(6); SFENCE();
      PRIO1(); MFMA8(a0, b00, b01); PRIO0();

      // ---- P2 ----
      GLOAD_LDS16(pB + ko, sp + 8192 + t * 8);
      GLOAD_LDS16(pB + (size_t)128 * K + ko, sp + 12288 + t * 8);
      WAIT_VM8();
      WAIT_LGKM(0);
      FENCE(); BAR();
      a0[0] = *reinterpret_cast<const bf16x8*>(sn + aoff);
      a0[1] = *reinterpret_cast<const bf16x8*>(sn + aoff + 1024);
      a0[2] = *reinterpret_cast<const bf16x8*>(sn + aoff + 2048);
      a0[3] = *reinterpret_cast<const bf16x8*>(sn + aoff + 3072);
      b00 = *reinterpret_cast<const bf16x8*>(sn + boff0);
      b01 = *reinterpret_cast<const bf16x8*>(sn + boff0 + 1024);
      SFENCE();
      PRIO1(); MFMA8(a1, b10, b11); PRIO0();
    }
  }

  for (int k = kb; k < NT; ++k) {
    const unsigned short* sl = &lds[(k & 3) * 16384];
    const bool pf = (k + 3 < NT);

    a1[0] = *reinterpret_cast<const bf16x8*>(sl + (aoff ^ 16));
    a1[1] = *reinterpret_cast<const bf16x8*>(sl + (aoff ^ 16) + 1024);
    a1[2] = *reinterpret_cast<const bf16x8*>(sl + (aoff ^ 16) + 2048);
    a1[3] = *reinterpret_cast<const bf16x8*>(sl + (aoff ^ 16) + 3072);
    b10 = *reinterpret_cast<const bf16x8*>(sl + (boff0 ^ 16));
    b11 = *reinterpret_cast<const bf16x8*>(sl + ((boff0 + 1024) ^ 16));
    if (pf) STAGE_A(k + 3);
    WAIT_LGKM(6); SFENCE();
    PRIO1(); MFMA8(a0, b00, b01); PRIO0();

    if (pf) {
      STAGE_B(k + 3);
      WAIT_VM8();
    } else if (k == NT - 3) {
      WAIT_VM4();
    } else if (k == NT - 2) {
      WAIT_VM0();
    }
    WAIT_LGKM(0);
    FENCE(); BAR();
    if (k + 1 < NT) {
      const unsigned short* sn = &lds[((k + 1) & 3) * 16384];
      a0[0] = *reinterpret_cast<const bf16x8*>(sn + aoff);
      a0[1] = *reinterpret_cast<const bf16x8*>(sn + aoff + 1024);
      a0[2] = *reinterpret_cast<const bf16x8*>(sn + aoff + 2048);
      a0[3] = *reinterpret_cast<const bf16x8*>(sn + aoff + 3072);
      b00 = *reinterpret_cast<const bf16x8*>(sn + boff0);
      b01 = *reinterpret_cast<const bf16x8*>(sn + boff0 + 1024);
    }
    SFENCE();
    PRIO1(); MFMA8(a1, b10, b11); PRIO0();
  }
#undef MFMA8
#undef STAGE_A
#undef STAGE_B

  const int ocol = bcol + wc * 64 + l31;
  const int rowb = brow + wr * 128 + 4 * hi;
#pragma unroll
  for (int m = 0; m < 4; ++m)
#pragma unroll
    for (int n = 0; n < 2; ++n)
#pragma unroll
      for (int rq = 0; rq < 4; ++rq)
#pragma unroll
        for (int j = 0; j < 4; ++j)
          C[(size_t)(rowb + m * 32 + 8 * rq + j) * N + (ocol + n * 32)] =
              acc[m][n][rq * 4 + j];
}

// ------------------------------ launch -------------------------------------

extern "C" void kernel_launch(void* const* d_in, const int* in_sizes, int n_in,
                              void* d_out, int out_size, void* d_ws,
                              size_t ws_size, hipStream_t stream) {
  const float* x  = (const float*)d_in[0];
  const float* w1 = (const float*)d_in[1];
  const float* w2 = (const float*)d_in[2];
  const float* w3 = (const float*)d_in[3];
  float* out = (float*)d_out;

  const int DIM = 4096, HID = 8192;
  const int M = in_sizes[0] / DIM;  // 8192

  char* xq  = (char*)d_ws;                              // M*DIM    (32 MB)
  char* w1q = xq + (size_t)M * DIM;                     // HID*DIM  (32 MB)
  char* w3q = w1q + (size_t)HID * DIM;                  // HID*DIM  (32 MB)
  unsigned short* w2b = (unsigned short*)(w3q + (size_t)HID * DIM);  // 64 MB
  unsigned short* h = w2b + (size_t)DIM * HID;          // M*HID bf16 (128 MB)
  float* sx  = (float*)(h + (size_t)M * HID);           // M
  float* sw1 = sx + M;                                  // HID
  float* sw3 = sw1 + HID;                               // HID

  quant_rows_i8_kernel<<<HID, 256, 0, stream>>>(w1, w1q, sw1, DIM, 1e-6f);
  quant_rows_i8_kernel<<<HID, 256, 0, stream>>>(w3, w3q, sw3, DIM, 1e-6f);
  quant_rows_i8_kernel<<<M, 256, 0, stream>>>(x, xq, sx, DIM, 1e-30f);
  quant_rows_bf16_kernel<<<DIM, 256, 0, stream>>>(w2, w2b, HID);

  gemm_i8_swiglu_kernel<<<dim3(HID / 128, M / 256), 512, 0, stream>>>(
      xq, w1q, w3q, sx, sw1, sw3, h, M, HID, DIM);
  gemm_bf16_kernel<<<dim3(DIM / 256, M / 256), 512, 0, stream>>>(
      h, w2b, out, M, DIM, HID);
}